// Round 6
// baseline (137.821 us; speedup 1.0000x reference)
//
#include <hip/hip_runtime.h>

// CharGRU2: 2-layer GRU (reset_after=true) + dense + softmax, fp32.
// B=2048, T=128, V=256, H=20, L=15.
//
// Round 18 = R16 math (exp2 pre-scaled gates, parallel DPP hops, pk_fma
// dots) restructured as a LAYER-SPLIT PRODUCER/CONSUMER PAIR:
//
//  Measured: R16 (2 waves/SIMD, same schedule) = 58% VALUBusy, ~440 idle
//  cy/iter that identical-schedule waves cannot fill (stagger null, R17's
//  1-wave ILP worse). Fix occupancy structurally: each batch uses TWO waves
//  - wave g   (role 0): L0 — rec0 dot, L0 gates, W0 gather pipeline,
//                        h0 -> LDS dbuf slot t&1
//  - wave g+4 (role 1): L1 — reads h0_{t-1} quads, xw1/rec1 dots, L1
//                        gates, own h1 LDS round trip, dense+softmax
//  pipelined one step apart, one __syncthreads per step (129 total, equal
//  on all waves; role-1 tail step t=TT runs with role-0 idle-but-present).
//  512-thread blocks (8 waves = 4 batches) x 512 blocks = 2 blocks/CU =
//  4 waves/SIMD, with 2 L0-role + 2 L1-role waves per SIMD (wave i ->
//  SIMD i&3): role-diverse streams fill each other's trans/LDS stalls.
//  Roles SHARE register arrays (wA/wB/cP/cT) to keep VGPR <= 128 (the
//  4-waves/SIMD allocation cliff).
//
// Layout recap: lane 16r+3u+p owns gate column p*20+(5r+u) (p=0:z 1:r 2:h~);
// home lane of unit j = 16*(j/5)+3*(j%5)+2; lane 16r+15 dups pos 14 and is
// excluded from LDS writes. Gate hops never cross a 16-lane DPP row.

#define BB 2048
#define TT 128
#define HH 20
#define LL 15
#define H3 60

typedef float v2f __attribute__((ext_vector_type(2)));

#if __has_builtin(__builtin_amdgcn_exp2f)
#define EXP2(x) __builtin_amdgcn_exp2f(x)
#else
#define EXP2(x) exp2f(x)
#endif

__device__ __forceinline__ float bclane(float v, int k) {
    return __int_as_float(__builtin_amdgcn_readlane(__float_as_int(v), k));
}
__device__ __forceinline__ float dpp_rshr1(float v) {
    return __int_as_float(__builtin_amdgcn_update_dpp(
        0, __float_as_int(v), 0x111, 0xF, 0xF, true));
}
__device__ __forceinline__ float dpp_rshr2(float v) {
    return __int_as_float(__builtin_amdgcn_update_dpp(
        0, __float_as_int(v), 0x112, 0xF, 0xF, true));
}
__device__ __forceinline__ float fast_rcp(float x) { return __builtin_amdgcn_rcpf(x); }
#define PIN(v) asm volatile("" : "+v"(v))

extern "C" __global__ __launch_bounds__(512, 4)
void gru2_kernel(const int* __restrict__ x, const float* __restrict__ W0,
                 const float* __restrict__ U0, const float* __restrict__ b0i,
                 const float* __restrict__ b0r, const float* __restrict__ W1,
                 const float* __restrict__ U1, const float* __restrict__ b1i,
                 const float* __restrict__ b1r, const float* __restrict__ Wd,
                 const float* __restrict__ bd, float* __restrict__ out)
{
    const int lane = threadIdx.x & 63;
    const int w    = threadIdx.x >> 6;                   // 0..7
    const int g    = w & 3;                              // batch group in block
    const int role = w >> 2;                             // 0: L0, 1: L1
    const int batch = blockIdx.x * 4 + g;

    const int row = lane >> 4;                           // DPP row 0..3
    const int pos = lane & 15;
    const int pc  = (pos < 15) ? pos : 14;               // lane 16r+15 dups 14
    const int u   = pc / 3;
    const int p3  = pc % 3;                              // 0:z 1:r 2:h~
    const int j   = row * 5 + u;                         // unit 0..19
    const bool home = (pos < 15) && (p3 == 2);
    const int col = p3 * 20 + j;

    // exp2 gate scale: z/r columns -log2e, h~ columns -2log2e
    const float gsc = (p3 == 2) ? -2.8853900817779268f : -1.4426950408889634f;

    // h0 handoff: double-buffered per batch-group; h1: role-1-private
    __shared__ __align__(16) float h0s[4][2][24];
    __shared__ __align__(16) float h1s[4][24];
    float* h0a = &h0s[g][0][0];
    float* h0b = &h0s[g][1][0];
    float* h1a = &h1s[g][0];
    const float4* q0a = (const float4*)h0a;
    const float4* q0b = (const float4*)h0b;
    const float4* q1a = (const float4*)h1a;

    // ---- role-shared register arrays ----
    // role 0: wA = U0 cols (scaled); wB unused
    // role 1: wA = W1 cols, wB = U1 cols (scaled)
    v2f wA[10], wB[10];
    v2f biasP;              // role0: {br0,0}; role1: {br1,0} (scaled)
    v2f biasT;              // role1: {bi1,0} (scaled)
    float xbias = 0.f;      // role0: bi0 (scaled)
    float4 cP[5], cT[5];    // persistent quads / transient h0 quads
    float h0 = 0.f, h1 = 0.f;

    int tokn2 = 0, tAlo = 0, tAhi = 0;
    float xw_cur = 0.f, xw_nxt = 0.f;

    if (role == 0) {
#pragma unroll
        for (int q = 0; q < 10; ++q) {
            const int k0 = (2 * q) * H3, k1 = (2 * q + 1) * H3;
            wA[q] = v2f{U0[k0 + col] * gsc, U0[k1 + col] * gsc};
        }
        biasP = v2f{b0r[col] * gsc, 0.f};
        xbias = b0i[col] * gsc;
        const int* xrow = x + batch * TT;
        tAlo = xrow[lane];
        tAhi = xrow[64 + lane];
        tokn2  = __builtin_amdgcn_readlane(tAlo, 2);
        xw_cur = fmaf(W0[__builtin_amdgcn_readlane(tAlo, 0) * H3 + col], gsc, xbias);
        xw_nxt = W0[__builtin_amdgcn_readlane(tAlo, 1) * H3 + col];
    } else {
#pragma unroll
        for (int q = 0; q < 10; ++q) {
            const int k0 = (2 * q) * H3, k1 = (2 * q + 1) * H3;
            wA[q] = v2f{W1[k0 + col] * gsc, W1[k1 + col] * gsc};
            wB[q] = v2f{U1[k0 + col] * gsc, U1[k1 + col] * gsc};
        }
        biasP = v2f{b1r[col] * gsc, 0.f};
        biasT = v2f{b1i[col] * gsc, 0.f};
    }
#pragma unroll
    for (int q = 0; q < 10; ++q) { PIN(wA[q]); PIN(wB[q]); }
#pragma unroll
    for (int q = 0; q < 5; ++q) cP[q] = float4{0.f, 0.f, 0.f, 0.f};

    // dot: 2 interleaved 5-deep pk chains, bias folded into first fma
#define DOT1(C, P, BIASV, OUT)                                                \
    {                                                                         \
        v2f aa = __builtin_elementwise_fma(v2f{C[0].x, C[0].y}, P[0], BIASV); \
        v2f ab = v2f{C[0].z, C[0].w} * P[1];                                  \
        _Pragma("unroll")                                                     \
        for (int q = 1; q < 5; ++q) {                                         \
            aa = __builtin_elementwise_fma(v2f{C[q].x, C[q].y}, P[2 * q], aa);\
            ab = __builtin_elementwise_fma(v2f{C[q].z, C[q].w}, P[2 * q + 1], ab);\
        }                                                                     \
        const v2f t_ = aa + ab;                                               \
        OUT = t_.x + t_.y;                                                    \
    }
    // gate block: one exp2/rcp stream serves z,r (sigmoid) and h~ (tanh)
#define GATES(XW, REC, H)                                                     \
    {                                                                         \
        const float e_  = EXP2((XW) + (REC));                                 \
        const float t_  = fast_rcp(1.f + e_);                                 \
        const float rv_ = dpp_rshr1(t_);                                      \
        const float zv_ = dpp_rshr2(t_);                                      \
        const float eh_ = EXP2(fmaf(rv_, (REC), (XW)));                       \
        const float th_ = fast_rcp(1.f + eh_);                                \
        const float hh_ = fmaf(2.f, th_, -1.f);                               \
        H = fmaf(zv_, (H) - hh_, hh_);                                        \
    }

    // ---- main loop: t = 0..TT (129 barriers on every wave) ----
    for (int t = 0; t <= TT; ++t) {
        __syncthreads();
        if (role == 0) {
            if (t < TT) {
                const int t3 = (t + 3 < TT) ? (t + 3) : (TT - 1);
                const float pf = W0[tokn2 * H3 + col];
                const int tokn3 =
                    __builtin_amdgcn_readlane(t3 < 64 ? tAlo : tAhi, t3 & 63);
                float rec0;
                DOT1(cP, wA, biasP, rec0);               // h0_{t-1} . U0 + br0
                GATES(xw_cur, rec0, h0);                 // -> h0_t
                float* hw = (t & 1) ? h0b : h0a;
                if (home) hw[j] = h0;
                const float4* qs = (t & 1) ? q0b : q0a;
#pragma unroll
                for (int q = 0; q < 5; ++q) cP[q] = qs[q]; // own next quads
                xw_cur = fmaf(xw_nxt, gsc, xbias);
                xw_nxt = pf; tokn2 = tokn3;
            }
        } else {
            if (t > 0) {
                const float4* qs = ((t - 1) & 1) ? q0b : q0a;
#pragma unroll
                for (int q = 0; q < 5; ++q) cT[q] = qs[q]; // h0_{t-1} quads
                float rec1;
                DOT1(cP, wB, biasP, rec1);               // h1_{t-2} . U1 + br1
                float xw1;
                DOT1(cT, wA, biasT, xw1);                // h0_{t-1} . W1 + bi1
                GATES(xw1, rec1, h1);                    // -> h1_{t-1}
                if (home) h1a[j] = h1;
#pragma unroll
                for (int q = 0; q < 5; ++q) cP[q] = q1a[q]; // own next quads
            }
        }
    }

    // ---- dense (h1 @ Wd + bd) + softmax: role 1 only, no barriers ----
    if (role == 1) {
        const int l = lane < LL ? lane : LL - 1;
        float acc = bd[l];
#pragma unroll
        for (int k = 0; k < HH; ++k)
            acc = fmaf(h1a[k], Wd[k * LL + l], acc);     // LDS broadcast reads

        float m = acc;
#pragma unroll
        for (int i = 0; i < LL; ++i) m = fmaxf(m, bclane(acc, i));
        const float e = __expf(acc - m);
        float s = 0.f;
#pragma unroll
        for (int i = 0; i < LL; ++i) s += bclane(e, i);
        const float pr = e * fast_rcp(s);

        if (lane < LL) out[batch * LL + lane] = pr;
    }
}

extern "C" void kernel_launch(void* const* d_in, const int* in_sizes, int n_in,
                              void* d_out, int out_size, void* d_ws, size_t ws_size,
                              hipStream_t stream) {
    const int*   x   = (const int*)  d_in[0];
    const float* W0  = (const float*)d_in[1];
    const float* U0  = (const float*)d_in[2];
    const float* b0i = (const float*)d_in[3];
    const float* b0r = (const float*)d_in[4];
    const float* W1  = (const float*)d_in[5];
    const float* U1  = (const float*)d_in[6];
    const float* b1i = (const float*)d_in[7];
    const float* b1r = (const float*)d_in[8];
    const float* Wd  = (const float*)d_in[9];
    const float* bd  = (const float*)d_in[10];
    // d_in[11] = drop_rate (identity), unused
    float* out = (float*)d_out;

    // 2 waves/batch (L0|L1), 4 batches/block (512 thr) -> 512 blocks =
    // 2 blocks/CU = 4 waves/SIMD with 2 L0-role + 2 L1-role waves each.
    dim3 grid(BB / 4), block(512);
    hipLaunchKernelGGL(gru2_kernel, grid, block, 0, stream,
                       x, W0, U0, b0i, b0r, W1, U1, b1i, b1r, Wd, bd, out);
}

// Round 7
// 130.324 us; speedup vs baseline: 1.0575x; 1.0575x over previous
//
#include <hip/hip_runtime.h>

// CharGRU2: 2-layer GRU (reset_after=true) + dense + softmax, fp32.
// B=2048, T=128, V=256, H=20, L=15.
//
// Round 19 = R16 (best: 55.7us — exp2 pre-scaled gates, parallel DPP hops,
// rec1 dot mid-iteration, LDS h-broadcast, staggered quad reads) with the
// dot chains FORCED to packed FP32 via inline asm:
//
//  R16's measured VALU issue (~150 insts/wave/iter from VALUBusy ledger)
//  exceeds the hand count assuming v_pk_fma_f32 emission (~90) — the
//  compiler is scalarizing the __builtin_elementwise_fma chains and/or
//  inserting marshalling movs. CDNA4 packed FP32 is full-rate (2 FLOP per
//  issue slot): forcing v_pk_fma_f32/v_pk_add_f32 with inline asm (non-
//  volatile, register-constrained, scheduler-transparent) halves dot issue.
//  ds_read_b128 quads sit in 4 contiguous VGPRs so {x,y}/{z,w} are already
//  even-aligned pairs — zero marshalling. Loop unroll 4 amortizes token-
//  pipeline plumbing.
//
//  Failed-experiment ledger (do not retry): R13 s_sleep stagger (null),
//  R14/15 readlane->SGPR dots (-29%), R17 1 wave/SIMD 2-batch ILP (-24%),
//  R18 layer-split producer/consumer 4 waves/SIMD (-31%, barrier lockstep).
//
// Layout recap: lane 16r+3u+p owns gate column p*20+(5r+u) (p=0:z 1:r 2:h~);
// home lane of unit j = 16*(j/5)+3*(j%5)+2; lane 16r+15 dups pos 14 and is
// excluded from LDS writes. Gate hops never cross a 16-lane DPP row.

#define BB 2048
#define TT 128
#define HH 20
#define LL 15
#define H3 60

typedef float v2f __attribute__((ext_vector_type(2)));

#if __has_builtin(__builtin_amdgcn_exp2f)
#define EXP2(x) __builtin_amdgcn_exp2f(x)
#else
#define EXP2(x) exp2f(x)
#endif

__device__ __forceinline__ float bclane(float v, int k) {
    return __int_as_float(__builtin_amdgcn_readlane(__float_as_int(v), k));
}
__device__ __forceinline__ float dpp_rshr1(float v) {
    return __int_as_float(__builtin_amdgcn_update_dpp(
        0, __float_as_int(v), 0x111, 0xF, 0xF, true));
}
__device__ __forceinline__ float dpp_rshr2(float v) {
    return __int_as_float(__builtin_amdgcn_update_dpp(
        0, __float_as_int(v), 0x112, 0xF, 0xF, true));
}
__device__ __forceinline__ float fast_rcp(float x) { return __builtin_amdgcn_rcpf(x); }

// forced packed fp32 math (VOP3P, full-rate on CDNA4)
__device__ __forceinline__ void pk_fma(v2f& acc, v2f a, v2f b) {
    asm("v_pk_fma_f32 %0, %1, %2, %0" : "+v"(acc) : "v"(a), "v"(b));
}
__device__ __forceinline__ v2f pk_add(v2f a, v2f b) {
    v2f d;
    asm("v_pk_add_f32 %0, %1, %2" : "=v"(d) : "v"(a), "v"(b));
    return d;
}

#define PIN(v) asm volatile("" : "+v"(v))
#define LDSFENCE() asm volatile("" ::: "memory")

extern "C" __global__ __launch_bounds__(256)
__attribute__((amdgpu_waves_per_eu(2, 2)))
void gru2_kernel(const int* __restrict__ x, const float* __restrict__ W0,
                 const float* __restrict__ U0, const float* __restrict__ b0i,
                 const float* __restrict__ b0r, const float* __restrict__ W1,
                 const float* __restrict__ U1, const float* __restrict__ b1i,
                 const float* __restrict__ b1r, const float* __restrict__ Wd,
                 const float* __restrict__ bd, float* __restrict__ out)
{
    const int lane = threadIdx.x & 63;
    const int w = threadIdx.x >> 6;
    const int b = blockIdx.x * 4 + w;                    // batch = wave id
    const int row = lane >> 4;                           // DPP row 0..3
    const int pos = lane & 15;                           // pos in row
    const int pc  = (pos < 15) ? pos : 14;               // lane 16r+15 dups pos 14
    const int u   = pc / 3;                              // unit-in-row 0..4
    const int p3  = pc % 3;                              // 0:z 1:r 2:h~
    const int j   = row * 5 + u;                         // unit 0..19
    const bool home = (pos < 15) && (p3 == 2);           // 20 h-home lanes
    const int col = p3 * 20 + j;                         // owned gate column

    // exp2 gate scale: z/r columns -log2e, h~ columns -2log2e
    const float gsc = (p3 == 2) ? -2.8853900817779268f : -1.4426950408889634f;

    // per-wave LDS staging of h0/h1 (wave-uniform broadcast reads)
    __shared__ __align__(16) float hbuf[4][2][24];
    float* h0buf = &hbuf[w][0][0];
    float* h1buf = &hbuf[w][1][0];
    const float4* h0q = (const float4*)h0buf;
    const float4* h1q = (const float4*)h1buf;
    if (home) { h0buf[j] = 0.f; h1buf[j] = 0.f; }
    LDSFENCE();

    // ---- weight columns (k-pair packed, pre-scaled) into VGPRs, pinned ----
    v2f u0p[10], w1p[10], u1p[10];
#pragma unroll
    for (int q = 0; q < 10; ++q) {
        const int k0 = (2 * q) * H3, k1 = (2 * q + 1) * H3;
        u0p[q] = v2f{U0[k0 + col] * gsc, U0[k1 + col] * gsc};
        w1p[q] = v2f{W1[k0 + col] * gsc, W1[k1 + col] * gsc};
        u1p[q] = v2f{U1[k0 + col] * gsc, U1[k1 + col] * gsc};
    }
#pragma unroll
    for (int q = 0; q < 10; ++q) { PIN(u0p[q]); PIN(w1p[q]); PIN(u1p[q]); }
    float bi0 = b0i[col] * gsc, br0 = b0r[col] * gsc;
    float bi1 = b1i[col] * gsc, br1 = b1r[col] * gsc;
    PIN(bi0); PIN(br0); PIN(bi1); PIN(br1);

    // ---- tokens ----
    const int* xrow = x + b * TT;
    const int tokA = xrow[lane];
    const int tokB = xrow[64 + lane];

    float h0 = 0.f, h1 = 0.f;                            // home lanes hold state

    // ---- W0 pipeline: row t ready(scaled), row t+1 raw, token t+2 staged ----
    const int tok0 = __builtin_amdgcn_readlane(tokA, 0);
    const int tok1 = __builtin_amdgcn_readlane(tokA, 1);
    int tokn2 = __builtin_amdgcn_readlane(tokA, 2);
    float xw_cur = fmaf(W0[tok0 * H3 + col], gsc, bi0);
    float xw_nxt = W0[tok1 * H3 + col];                  // raw

    float4 c0[5], c1[5];                                 // register-staged h quads
    float rec0, xw1, rec1;                               // carried dot results

    // dots from c0 (=h0_t): rec0 (U0) + xw1 (W1), forced v_pk_fma_f32
#define DOT01()                                                               \
    {                                                                         \
        v2f a0a = v2f{br0, 0.f}, a0b = v2f{0.f, 0.f};                         \
        v2f a1a = v2f{bi1, 0.f}, a1b = v2f{0.f, 0.f};                         \
        _Pragma("unroll")                                                     \
        for (int q = 0; q < 5; ++q) {                                         \
            const v2f hA = v2f{c0[q].x, c0[q].y}, hB = v2f{c0[q].z, c0[q].w}; \
            pk_fma(a0a, hA, u0p[2 * q]);                                      \
            pk_fma(a0b, hB, u0p[2 * q + 1]);                                  \
            pk_fma(a1a, hA, w1p[2 * q]);                                      \
            pk_fma(a1b, hB, w1p[2 * q + 1]);                                  \
        }                                                                     \
        { const v2f t = pk_add(a0a, a0b); rec0 = t.x + t.y; }                 \
        { const v2f t = pk_add(a1a, a1b); xw1  = t.x + t.y; }                 \
    }
    // dot from c1 (=h1_{t-1}): rec1 (U1)
#define DOT2()                                                                \
    {                                                                         \
        v2f a2a = v2f{br1, 0.f}, a2b = v2f{0.f, 0.f};                         \
        _Pragma("unroll")                                                     \
        for (int q = 0; q < 5; ++q) {                                         \
            const v2f gA = v2f{c1[q].x, c1[q].y}, gB = v2f{c1[q].z, c1[q].w}; \
            pk_fma(a2a, gA, u1p[2 * q]);                                      \
            pk_fma(a2b, gB, u1p[2 * q + 1]);                                  \
        }                                                                     \
        { const v2f t = pk_add(a2a, a2b); rec1 = t.x + t.y; }                 \
    }
    // gate block: one exp2/rcp stream serves z,r (sigmoid) and h~ (tanh)
#define GATES(XW, REC, H)                                                     \
    {                                                                         \
        const float e_  = EXP2((XW) + (REC));                                 \
        const float t_  = fast_rcp(1.f + e_);                                 \
        const float rv_ = dpp_rshr1(t_);                                      \
        const float zv_ = dpp_rshr2(t_);                                      \
        const float eh_ = EXP2(fmaf(rv_, (REC), (XW)));                       \
        const float th_ = fast_rcp(1.f + eh_);                                \
        const float hh_ = fmaf(2.f, th_, -1.f);                               \
        H = fmaf(zv_, (H) - hh_, hh_);                                        \
    }

    // ---- prologue: L0 for t=0 (h0_{-1}=0 -> rec0 = br0); c1 = zeros ----
    {
        const float pf = W0[tokn2 * H3 + col];
        const int tokn3 = __builtin_amdgcn_readlane(tokA, 3);
        GATES(xw_cur, br0, h0);
        if (home) h0buf[j] = h0;
        LDSFENCE();
#pragma unroll
        for (int q = 0; q < 5; ++q) { c0[q] = h0q[q]; c1[q] = h1q[q]; }
        xw_cur = fmaf(xw_nxt, gsc, bi0); xw_nxt = pf; tokn2 = tokn3;
        DOT01();                                         // rec0/xw1 for i=1
    }

    // ---- main loop: i = 1..127 — L0 gates / rec1 dot / L1 gates / tail dots
#pragma unroll 4
    for (int i = 1; i < TT; ++i) {
        const int t3 = (i + 3 < TT) ? (i + 3) : (TT - 1);
        const float pf = W0[tokn2 * H3 + col];
        const int tokn3 = __builtin_amdgcn_readlane(t3 < 64 ? tokA : tokB, t3 & 63);

        // ---- L0 gates (t=i): rec0/xw_cur carried, chain starts now ----
        GATES(xw_cur, rec0, h0);
        if (home) h0buf[j] = h0;
        LDSFENCE();
#pragma unroll
        for (int q = 0; q < 5; ++q) c0[q] = h0q[q];      // next h0 quads

        // ---- rec1 dot: c1 read one full iteration ago (latency hidden);
        //      chain hides under L0's trans latency before L1 needs it ----
        DOT2();

        // ---- L1 gates (t=i-1) ----
        GATES(xw1, rec1, h1);
        if (home) h1buf[j] = h1;
        LDSFENCE();
#pragma unroll
        for (int q = 0; q < 5; ++q) c1[q] = h1q[q];      // next h1 quads

        // rotate W0 pipeline (scale applied here: fma, not add)
        xw_cur = fmaf(xw_nxt, gsc, bi0); xw_nxt = pf; tokn2 = tokn3;

        // ---- tail dots for i+1: consume c0 (gap = rec1 dot + L1 gates) ----
        DOT01();
    }

    // ---- epilogue: L1 for t=127 (xw1 carried; rec1 from final c1) ----
    {
        DOT2();
        GATES(xw1, rec1, h1);
        if (home) h1buf[j] = h1;                         // final h1
        LDSFENCE();
    }

    // ---- dense (h1 @ Wd + bd) + softmax, lanes 0..14 ----
    const int l = lane < LL ? lane : LL - 1;
    float acc = bd[l];
#pragma unroll
    for (int k = 0; k < HH; ++k)
        acc = fmaf(h1buf[k], Wd[k * LL + l], acc);       // LDS broadcast reads

    float m = acc;
#pragma unroll
    for (int i = 0; i < LL; ++i) m = fmaxf(m, bclane(acc, i));
    const float e = __expf(acc - m);
    float s = 0.f;
#pragma unroll
    for (int i = 0; i < LL; ++i) s += bclane(e, i);
    const float pr = e * fast_rcp(s);

    if (lane < LL) out[b * LL + lane] = pr;
}

extern "C" void kernel_launch(void* const* d_in, const int* in_sizes, int n_in,
                              void* d_out, int out_size, void* d_ws, size_t ws_size,
                              hipStream_t stream) {
    const int*   x   = (const int*)  d_in[0];
    const float* W0  = (const float*)d_in[1];
    const float* U0  = (const float*)d_in[2];
    const float* b0i = (const float*)d_in[3];
    const float* b0r = (const float*)d_in[4];
    const float* W1  = (const float*)d_in[5];
    const float* U1  = (const float*)d_in[6];
    const float* b1i = (const float*)d_in[7];
    const float* b1r = (const float*)d_in[8];
    const float* Wd  = (const float*)d_in[9];
    const float* bd  = (const float*)d_in[10];
    // d_in[11] = drop_rate (identity), unused
    float* out = (float*)d_out;

    // 1 batch/wave, 4 waves/block -> 512 blocks = 2 blocks/CU = 2 waves/SIMD.
    dim3 grid(BB / 4), block(256);
    hipLaunchKernelGGL(gru2_kernel, grid, block, 0, stream,
                       x, W0, U0, b0i, b0r, W1, U1, b1i, b1r, Wd, bd, out);
}